// Round 7
// baseline (432.902 us; speedup 1.0000x reference)
//
#include <hip/hip_runtime.h>
#include <hip/hip_bf16.h>
#include <math.h>

// B=4, L=1024, D=1024, H=16, HD=64, SCALE=1/8
// scores[l,r] = (q.k + q.e[l-r] + k.e[l-r]) * SCALE; softmax over r; @V.
#define Bq 4
#define Lq 1024
#define Dq 1024
#define Hq 16
#define HDq 64
#define BHq (Bq * Hq)
#define HEAD_ELEMS ((size_t)BHq * Lq * HDq)   // 4194304 elements per tensor

typedef short bf16x8 __attribute__((ext_vector_type(8)));
typedef _Float16 f16x8 __attribute__((ext_vector_type(8)));
typedef float f32x4 __attribute__((ext_vector_type(4)));
#define MFMA16B(A, B, C) __builtin_amdgcn_mfma_f32_16x16x32_bf16(A, B, C, 0, 0, 0)
#define MFMA16F(A, B, C) __builtin_amdgcn_mfma_f32_16x16x32_f16(A, B, C, 0, 0, 0)

__device__ __forceinline__ unsigned short f2bf(float x) {
  unsigned u = __builtin_bit_cast(unsigned, x);
  unsigned r = u + 0x7FFFu + ((u >> 16) & 1u);   // RNE (finite inputs)
  return (unsigned short)(r >> 16);
}
__device__ __forceinline__ float bf2f(unsigned short s) {
  unsigned u = ((unsigned)s) << 16;
  return __builtin_bit_cast(float, u);
}
__device__ __forceinline__ unsigned short f2h(float x) {
  _Float16 h = (_Float16)x;                      // RNE
  return __builtin_bit_cast(unsigned short, h);
}

// ---------------------------------------------------------------------------
// P1: X fp32 -> fp16 (straight copy).  4096x1024.
// ---------------------------------------------------------------------------
__global__ __launch_bounds__(256) void x_prep(const float* __restrict__ X,
                                              unsigned short* __restrict__ Xh) {
  size_t i = (size_t)blockIdx.x * 256 + threadIdx.x;  // unit of 4 el
  float4 f = *(const float4*)(X + i * 4);
  uint2 pk;
  pk.x = (unsigned)f2h(f.x) | ((unsigned)f2h(f.y) << 16);
  pk.y = (unsigned)f2h(f.z) | ((unsigned)f2h(f.w) << 16);
  *(uint2*)(Xh + i * 4) = pk;
}

// ---------------------------------------------------------------------------
// P2: W fp32 [1024][3072] -> Wt fp16 [3072][1024] (transpose via LDS tile).
// ---------------------------------------------------------------------------
__global__ __launch_bounds__(256) void wt_prep(const float* __restrict__ W,
                                               unsigned short* __restrict__ Wt) {
  __shared__ unsigned short tile[64 * 72];
  const int k0 = blockIdx.x * 64;   // 16
  const int n0 = blockIdx.y * 64;   // 48
  const int tid = threadIdx.x;
#pragma unroll
  for (int it = 0; it < 4; it++) {
    int idx = tid + it * 256;       // 1024 units of 4 el
    int r = idx >> 4, c4 = (idx & 15) * 4;   // r = k row, c4 = n col
    float4 f = *(const float4*)(W + (size_t)(k0 + r) * 3072 + n0 + c4);
    unsigned w0 = (unsigned)f2h(f.x) | ((unsigned)f2h(f.y) << 16);
    unsigned w1 = (unsigned)f2h(f.z) | ((unsigned)f2h(f.w) << 16);
    *(unsigned*)&tile[r * 72 + c4] = w0;
    *(unsigned*)&tile[r * 72 + c4 + 2] = w1;
  }
  __syncthreads();
#pragma unroll
  for (int it = 0; it < 4; it++) {
    int u = tid + it * 256;         // 1024 units of 4 el (k-dir)
    int n = u >> 4, k4 = (u & 15) * 4;
    unsigned short e0 = tile[(k4 + 0) * 72 + n];
    unsigned short e1 = tile[(k4 + 1) * 72 + n];
    unsigned short e2 = tile[(k4 + 2) * 72 + n];
    unsigned short e3 = tile[(k4 + 3) * 72 + n];
    uint2 pk;
    pk.x = (unsigned)e0 | ((unsigned)e1 << 16);
    pk.y = (unsigned)e2 | ((unsigned)e3 << 16);
    *(uint2*)(Wt + (size_t)(n0 + n) * 1024 + k0 + k4) = pk;
  }
}

// ---------------------------------------------------------------------------
// P3: dist_emb fp32 -> bf16.
// ---------------------------------------------------------------------------
__global__ __launch_bounds__(256) void emb_prep(const float* __restrict__ e,
                                                unsigned short* __restrict__ o) {
  int i = blockIdx.x * 256 + threadIdx.x;
  if (i < 2047 * 64) o[i] = f2bf(e[i]);
}

// ---------------------------------------------------------------------------
// K1: QKV projection, fp16 MFMA (m97 structure).  Unchanged (R4-proven).
// ---------------------------------------------------------------------------
__global__ __launch_bounds__(256, 2) void qkv_mfma(
    const unsigned short* __restrict__ Xh, const unsigned short* __restrict__ Wt,
    const float* __restrict__ bias, unsigned short* __restrict__ qkvg) {
  __shared__ __align__(16) char smem[32768];
  unsigned short* Asm = (unsigned short*)smem;            // [128][32] (no pad: glds)
  unsigned short* Bsm = (unsigned short*)(smem + 8192);   // [128][32]
  unsigned short* Cs  = (unsigned short*)smem;            // epilogue [128][128]

  const int tid = threadIdx.x;
  const int w = tid >> 6, lane = tid & 63;
  const int col = lane & 15, quad = lane >> 4;
  const int wm = (w >> 1) * 64, wn = (w & 1) * 64;
  const int bn = blockIdx.x * 128, bm = blockIdx.y * 128;

  const unsigned short* Ag = Xh + (size_t)bm * 1024;
  const unsigned short* Bg = Wt + (size_t)bn * 1024;
  const int ldrow = w * 32 + (lane >> 2);   // + it*16
  const int ldoff = (lane & 3) * 8;         // element offset in k

  f32x4 acc[4][4];
#pragma unroll
  for (int i = 0; i < 4; i++)
#pragma unroll
    for (int j = 0; j < 4; j++) acc[i][j] = (f32x4){0.f, 0.f, 0.f, 0.f};

  for (int k0 = 0; k0 < 1024; k0 += 32) {
    __syncthreads();
#pragma unroll
    for (int it = 0; it < 2; it++) {
      const unsigned short* ga = Ag + (size_t)(ldrow + it * 16) * 1024 + k0 + ldoff;
      const unsigned short* gb = Bg + (size_t)(ldrow + it * 16) * 1024 + k0 + ldoff;
      __builtin_amdgcn_global_load_lds(
          (const __attribute__((address_space(1))) unsigned*)ga,
          (__attribute__((address_space(3))) unsigned*)(Asm + (w * 32 + it * 16) * 32),
          16, 0, 0);
      __builtin_amdgcn_global_load_lds(
          (const __attribute__((address_space(1))) unsigned*)gb,
          (__attribute__((address_space(3))) unsigned*)(Bsm + (w * 32 + it * 16) * 32),
          16, 0, 0);
    }
    __syncthreads();
    f16x8 af[4], bf[4];
#pragma unroll
    for (int i = 0; i < 4; i++)
      af[i] = *(const f16x8*)&Asm[(wm + i * 16 + col) * 32 + quad * 8];
#pragma unroll
    for (int j = 0; j < 4; j++)
      bf[j] = *(const f16x8*)&Bsm[(wn + j * 16 + col) * 32 + quad * 8];
#pragma unroll
    for (int i = 0; i < 4; i++)
#pragma unroll
      for (int j = 0; j < 4; j++)
        acc[i][j] = MFMA16F(af[i], bf[j], acc[i][j]);
  }

  float bj[4];
#pragma unroll
  for (int j = 0; j < 4; j++) bj[j] = bias[bn + wn + j * 16 + col];

  __syncthreads();   // staging LDS dead; reuse as Cs
#pragma unroll
  for (int i = 0; i < 4; i++)
#pragma unroll
    for (int j = 0; j < 4; j++)
#pragma unroll
      for (int k = 0; k < 4; k++)
        Cs[(wm + i * 16 + quad * 4 + k) * 128 + wn + j * 16 + col] =
            f2bf(acc[i][j][k] + bj[j]);
  __syncthreads();

  const int t = bn >> 10;                       // uniform per block
  unsigned short* dst_base = qkvg + (size_t)t * HEAD_ELEMS;
#pragma unroll
  for (int it = 0; it < 8; it++) {
    int u = tid + it * 256;                     // 2048 units of 8 el
    int row = u >> 4, c8 = (u & 15) * 8;
    int m = bm + row;
    int n = bn + c8;
    int b = m >> 10, l = m & 1023;
    int cc = n & 1023, h = cc >> 6, d0 = cc & 63;
    uint4 val = *(const uint4*)&Cs[row * 128 + c8];
    *(uint4*)(dst_base + (((size_t)(b * 16 + h) * 1024 + l) * 64 + d0)) = val;
  }
}

// ---------------------------------------------------------------------------
// P4: V bf16 [bh][l][64] -> VT bf16 [bh][d][1024].
// ---------------------------------------------------------------------------
__global__ __launch_bounds__(256) void vt_prep_bf(const unsigned short* __restrict__ vg,
                                                  unsigned short* __restrict__ vtg) {
  __shared__ unsigned short tile[64 * 72];
  const int bh = blockIdx.x;
  const int rt = blockIdx.y * 64;
  const int tid = threadIdx.x;
  const unsigned short* src = vg + ((size_t)bh * Lq + rt) * HDq;
#pragma unroll
  for (int it = 0; it < 2; it++) {
    int idx = tid + it * 256;       // 512 units of 8 el
    int r = idx >> 3, o = (idx & 7) * 8;
    *(uint4*)&tile[r * 72 + o] = *(const uint4*)(src + (size_t)r * 64 + o);
  }
  __syncthreads();
  unsigned short* dst = vtg + (size_t)bh * HDq * Lq;
#pragma unroll
  for (int it = 0; it < 4; it++) {
    int u = tid + it * 256;         // 1024 units of 4 r
    int d = u >> 4, r4 = (u & 15) * 4;
    unsigned short e0 = tile[(r4 + 0) * 72 + d];
    unsigned short e1 = tile[(r4 + 1) * 72 + d];
    unsigned short e2 = tile[(r4 + 2) * 72 + d];
    unsigned short e3 = tile[(r4 + 3) * 72 + d];
    uint2 pk;
    pk.x = (unsigned)e0 | ((unsigned)e1 << 16);
    pk.y = (unsigned)e2 | ((unsigned)e3 << 16);
    *(uint2*)(dst + (size_t)d * Lq + rt + r4) = pk;
  }
}

// ---------------------------------------------------------------------------
// K2: MFMA flash attention (R6 dataflow).  R7 deltas:
// (1) Ps aliases Qs (Q consumed into registers in prologue) — frees 9216 B.
// (2) B12 stride 136 -> 132 shorts (word-stride 66 === 2 mod 32: softmax b32
//     reads become uniform 2-way, free).
// LDS 53760 B -> 3 blocks/CU (12 waves/CU), launch_bounds(256,3).
// ---------------------------------------------------------------------------
__global__ __launch_bounds__(256, 3) void attn_mfma(
    const unsigned short* __restrict__ qg, const unsigned short* __restrict__ kg,
    const unsigned short* __restrict__ vtg, const unsigned short* __restrict__ emb,
    float* __restrict__ out) {
  __shared__ __align__(16) char smem[53760];
  unsigned short* Qs  = (unsigned short*)smem;             // [64][72] (prologue only)
  unsigned short* Ps  = (unsigned short*)smem;             // alias: loop-time P
  unsigned short* Ks  = (unsigned short*)(smem + 9216);    // [64][72]
  unsigned short* VTs = (unsigned short*)(smem + 18432);   // [64 d][72]
  unsigned short* Pb  = (unsigned short*)(smem + 27648);   // [64][72] new band half
  unsigned short* B12 = (unsigned short*)(smem + 36864);   // [64][132] interleaved

  const int bh = blockIdx.x;
  const int l0 = blockIdx.y * 64;
  const int tid = threadIdx.x;
  const int w = tid >> 6, lane = tid & 63;
  const int col = lane & 15, quad = lane >> 4;
  const int lw = w * 16;

  const unsigned short* Qg = qg + ((size_t)bh * Lq + l0) * HDq;
  const unsigned short* Kg = kg + (size_t)bh * Lq * HDq;
  const unsigned short* VTgh = vtg + (size_t)bh * HDq * Lq;

  // ---- prologue: stage Q + upper band half (delta rows 64..127 of chunk 0) ----
#pragma unroll
  for (int it = 0; it < 2; it++) {
    int idx = tid + it * 256;       // 512 units of 8 el
    int r = idx >> 3, o = (idx & 7) * 8;
    *(uint4*)&Qs[r * 72 + o] = *(const uint4*)(Qg + (size_t)r * 64 + o);
    // upper half of chunk-0 band: emb rows (l0 + 960) + 64 + r
    int g = min(l0 + 1024 + r, 2046);
    *(uint4*)&Pb[r * 72 + o] = *(const uint4*)(emb + (size_t)g * 64 + o);
  }
  __syncthreads();

  bf16x8 qf[2];
#pragma unroll
  for (int ks = 0; ks < 2; ks++)
    qf[ks] = *(const bf16x8*)&Qs[(lw + col) * 72 + quad * 8 + ks * 32];

  // carried fragments: band rows 64+dt*16+col (dt'=4..7) of the current chunk
  bf16x8 sav[4][2];
#pragma unroll
  for (int dm = 0; dm < 4; dm++)
#pragma unroll
    for (int ks = 0; ks < 2; ks++)
      sav[dm][ks] = *(const bf16x8*)&Pb[(dm * 16 + col) * 72 + quad * 8 + ks * 32];

  f32x4 oacc[4];
#pragma unroll
  for (int nt = 0; nt < 4; nt++) oacc[nt] = (f32x4){0.f, 0.f, 0.f, 0.f};
  float mrow[4] = {-1e30f, -1e30f, -1e30f, -1e30f};
  float lrow[4] = {0.f, 0.f, 0.f, 0.f};

  for (int ch = 0; ch < 16; ch++) {
    const int r0 = ch * 64;
    __syncthreads();   // prior chunk's LDS reads (incl. B12, Pb, Ps) complete

    // ---- stage K chunk ----
#pragma unroll
    for (int it = 0; it < 2; it++) {
      int idx = tid + it * 256;
      int r = idx >> 3, o = (idx & 7) * 8;
      *(uint4*)&Ks[r * 72 + o] = *(const uint4*)(Kg + (size_t)(r0 + r) * 64 + o);
    }
    // ---- stage VT chunk ----
#pragma unroll
    for (int it = 0; it < 2; it++) {
      int idx = tid + it * 256;
      int d = idx >> 3, o = (idx & 7) * 8;
      *(uint4*)&VTs[d * 72 + o] = *(const uint4*)(VTgh + (size_t)d * Lq + r0 + o);
    }
    // ---- stage NEW band half: delta rows 0..63 = emb rows pb0 + r ----
    const int pb0 = l0 - r0 + 960;
#pragma unroll
    for (int it = 0; it < 2; it++) {
      int idx = tid + it * 256;     // 512 units of 8 el
      int r = idx >> 3, o = (idx & 7) * 8;
      *(uint4*)&Pb[r * 72 + o] = *(const uint4*)(emb + (size_t)(pb0 + r) * 64 + o);
    }
    __syncthreads();   // staging visible

    // ---- S = Q K^T ----
    bf16x8 kf[4][2];
#pragma unroll
    for (int rt = 0; rt < 4; rt++)
#pragma unroll
      for (int ks = 0; ks < 2; ks++)
        kf[rt][ks] = *(const bf16x8*)&Ks[(rt * 16 + col) * 72 + quad * 8 + ks * 32];
    f32x4 sac[4];
#pragma unroll
    for (int rt = 0; rt < 4; rt++) {
      f32x4 z = (f32x4){0.f, 0.f, 0.f, 0.f};
      z = MFMA16B(qf[0], kf[rt][0], z);
      z = MFMA16B(qf[1], kf[rt][1], z);
      sac[rt] = z;
    }

    bf16x8 kaf[2];
#pragma unroll
    for (int ks = 0; ks < 2; ks++)
      kaf[ks] = *(const bf16x8*)&Ks[(lw + col) * 72 + quad * 8 + ks * 32];

    // ---- D1/D2 GEMMs + shear scatter into B12 ----
    bf16x8 fresh[4][2];
#pragma unroll
    for (int dm = 0; dm < 4; dm++)
#pragma unroll
      for (int ks = 0; ks < 2; ks++)
        fresh[dm][ks] = *(const bf16x8*)&Pb[(dm * 16 + col) * 72 + quad * 8 + ks * 32];

#pragma unroll
    for (int dt = 0; dt < 8; dt++) {
      bf16x8 pbf0 = (dt < 4) ? fresh[dt & 3][0] : sav[dt & 3][0];
      bf16x8 pbf1 = (dt < 4) ? fresh[dt & 3][1] : sav[dt & 3][1];
      f32x4 z = (f32x4){0.f, 0.f, 0.f, 0.f};
      f32x4 y = (f32x4){0.f, 0.f, 0.f, 0.f};
      z = MFMA16B(qf[0], pbf0, z);
      z = MFMA16B(qf[1], pbf1, z);     // D1[l][delta]
      y = MFMA16B(kaf[0], pbf0, y);
      y = MFMA16B(kaf[1], pbf1, y);    // D2[r][delta]
      const int dcol = dt * 16 + col;  // delta band index j = l - r + 63
#pragma unroll
      for (int k = 0; k < 4; k++) {
        int l1 = lw + quad * 4 + k;
        int r1 = l1 - dcol + 63;
        if (r1 >= 0 && r1 < 64) B12[l1 * 132 + 2 * r1] = f2bf(z[k]);
        int r2 = lw + quad * 4 + k;
        int l2 = dcol - 63 + r2;
        if (l2 >= 0 && l2 < 64) B12[l2 * 132 + 2 * r2 + 1] = f2bf(y[k]);
      }
    }
    // carry: this chunk's fresh lower half == next chunk's upper half
#pragma unroll
    for (int dm = 0; dm < 4; dm++)
#pragma unroll
      for (int ks = 0; ks < 2; ks++)
        sav[dm][ks] = fresh[dm][ks];
    __syncthreads();   // bias writes visible (B12 is cross-wave)

    // ---- online softmax (C-layout: row = quad*4+k, col = lane&15) ----
    float p[4][4];
    float alpha[4];
#pragma unroll
    for (int k = 0; k < 4; k++) {
      int l1 = lw + quad * 4 + k;
      float st[4];
#pragma unroll
      for (int rt = 0; rt < 4; rt++) {
        int r = rt * 16 + col;
        unsigned pr = *(const unsigned*)&B12[l1 * 132 + 2 * r];
        float bias = bf2f((unsigned short)(pr & 0xFFFFu)) +
                     bf2f((unsigned short)(pr >> 16));
        st[rt] = (sac[rt][k] + bias) * 0.125f;
      }
      float mx = fmaxf(fmaxf(st[0], st[1]), fmaxf(st[2], st[3]));
      mx = fmaxf(mx, __shfl_xor(mx, 1));
      mx = fmaxf(mx, __shfl_xor(mx, 2));
      mx = fmaxf(mx, __shfl_xor(mx, 4));
      mx = fmaxf(mx, __shfl_xor(mx, 8));
      float mnew = fmaxf(mrow[k], mx);
      float a = __expf(mrow[k] - mnew);
      mrow[k] = mnew;
      alpha[k] = a;
      float ls = 0.f;
#pragma unroll
      for (int rt = 0; rt < 4; rt++) {
        p[rt][k] = __expf(st[rt] - mnew);
        ls += p[rt][k];
      }
      lrow[k] = lrow[k] * a + ls;
    }
#pragma unroll
    for (int nt = 0; nt < 4; nt++)
#pragma unroll
      for (int k = 0; k < 4; k++) oacc[nt][k] *= alpha[k];

    // ---- P -> LDS (A-layout), same-wave rows only (Ps aliases dead Qs) ----
#pragma unroll
    for (int rt = 0; rt < 4; rt++)
#pragma unroll
      for (int k = 0; k < 4; k++)
        Ps[(lw + quad * 4 + k) * 72 + rt * 16 + col] = f2bf(p[rt][k]);

    // ---- PV ----
    bf16x8 pf[2];
#pragma unroll
    for (int ks = 0; ks < 2; ks++)
      pf[ks] = *(const bf16x8*)&Ps[(lw + col) * 72 + quad * 8 + ks * 32];
#pragma unroll
    for (int nt = 0; nt < 4; nt++) {
      bf16x8 v0 = *(const bf16x8*)&VTs[(nt * 16 + col) * 72 + quad * 8];
      bf16x8 v1 = *(const bf16x8*)&VTs[(nt * 16 + col) * 72 + quad * 8 + 32];
      oacc[nt] = MFMA16B(pf[0], v0, oacc[nt]);
      oacc[nt] = MFMA16B(pf[1], v1, oacc[nt]);
    }
  }

  // ---- epilogue ----
  float inv[4];
#pragma unroll
  for (int k = 0; k < 4; k++) {
    float t = lrow[k];
    t += __shfl_xor(t, 1);
    t += __shfl_xor(t, 2);
    t += __shfl_xor(t, 4);
    t += __shfl_xor(t, 8);
    inv[k] = 1.0f / t;
  }
  const int b = bh >> 4, h = bh & 15;
#pragma unroll
  for (int nt = 0; nt < 4; nt++) {
#pragma unroll
    for (int k = 0; k < 4; k++) {
      int lg = l0 + lw + quad * 4 + k;
      int d = nt * 16 + col;
      out[(((size_t)b * Lq + lg) * Hq + h) * HDq + d] = oacc[nt][k] * inv[k];
    }
  }
}

// ---------------------------------------------------------------------------
extern "C" void kernel_launch(void* const* d_in, const int* in_sizes, int n_in,
                              void* d_out, int out_size, void* d_ws, size_t ws_size,
                              hipStream_t stream) {
  const float* x        = (const float*)d_in[0];
  const float* Wqkv     = (const float*)d_in[1];
  const float* bqkv     = (const float*)d_in[2];
  const float* dist_emb = (const float*)d_in[3];
  float* out = (float*)d_out;

  unsigned short* Xh   = (unsigned short*)d_ws;                              // 8 MB
  unsigned short* Wt   = (unsigned short*)((char*)d_ws + (8u << 20));        // 6 MB
  unsigned short* qkvg = (unsigned short*)((char*)d_ws + (16u << 20));       // 24 MB
  unsigned short* vtg  = (unsigned short*)((char*)d_ws + (40u << 20));       // 8 MB
  unsigned short* emb  = (unsigned short*)((char*)d_ws + (48u << 20));       // 256 KB

  x_prep<<<dim3(4096), dim3(256), 0, stream>>>(x, Xh);
  wt_prep<<<dim3(16, 48), dim3(256), 0, stream>>>(Wqkv, Wt);
  emb_prep<<<dim3(512), dim3(256), 0, stream>>>(dist_emb, emb);

  qkv_mfma<<<dim3(24, 32), dim3(256), 0, stream>>>(Xh, Wt, bqkv, qkvg);

  vt_prep_bf<<<dim3(BHq, Lq / 64), dim3(256), 0, stream>>>(qkvg + 2 * HEAD_ELEMS, vtg);

  attn_mfma<<<dim3(BHq, Lq / 64), dim3(256), 0, stream>>>(
      qkvg, qkvg + HEAD_ELEMS, vtg, emb, out);
}

// Round 8
// 262.980 us; speedup vs baseline: 1.6461x; 1.6461x over previous
//
#include <hip/hip_runtime.h>
#include <hip/hip_bf16.h>
#include <math.h>

// B=4, L=1024, D=1024, H=16, HD=64, SCALE=1/8
// scores[l,r] = (q.k + q.e[l-r] + k.e[l-r]) * SCALE; softmax over r; @V.
#define Bq 4
#define Lq 1024
#define Dq 1024
#define Hq 16
#define HDq 64
#define BHq (Bq * Hq)
#define HEAD_ELEMS ((size_t)BHq * Lq * HDq)   // 4194304 elements per tensor

typedef short bf16x8 __attribute__((ext_vector_type(8)));
typedef _Float16 f16x8 __attribute__((ext_vector_type(8)));
typedef float f32x4 __attribute__((ext_vector_type(4)));
#define MFMA16B(A, B, C) __builtin_amdgcn_mfma_f32_16x16x32_bf16(A, B, C, 0, 0, 0)
#define MFMA16F(A, B, C) __builtin_amdgcn_mfma_f32_16x16x32_f16(A, B, C, 0, 0, 0)

__device__ __forceinline__ unsigned short f2bf(float x) {
  unsigned u = __builtin_bit_cast(unsigned, x);
  unsigned r = u + 0x7FFFu + ((u >> 16) & 1u);   // RNE (finite inputs)
  return (unsigned short)(r >> 16);
}
__device__ __forceinline__ float bf2f(unsigned short s) {
  unsigned u = ((unsigned)s) << 16;
  return __builtin_bit_cast(float, u);
}
__device__ __forceinline__ unsigned short f2h(float x) {
  _Float16 h = (_Float16)x;                      // RNE
  return __builtin_bit_cast(unsigned short, h);
}

// ---------------------------------------------------------------------------
// P1: X fp32 -> fp16 (straight copy).  4096x1024.
// ---------------------------------------------------------------------------
__global__ __launch_bounds__(256) void x_prep(const float* __restrict__ X,
                                              unsigned short* __restrict__ Xh) {
  size_t i = (size_t)blockIdx.x * 256 + threadIdx.x;  // unit of 4 el
  float4 f = *(const float4*)(X + i * 4);
  uint2 pk;
  pk.x = (unsigned)f2h(f.x) | ((unsigned)f2h(f.y) << 16);
  pk.y = (unsigned)f2h(f.z) | ((unsigned)f2h(f.w) << 16);
  *(uint2*)(Xh + i * 4) = pk;
}

// ---------------------------------------------------------------------------
// P2: W fp32 [1024][3072] -> Wt fp16 [3072][1024] (transpose via LDS tile).
// ---------------------------------------------------------------------------
__global__ __launch_bounds__(256) void wt_prep(const float* __restrict__ W,
                                               unsigned short* __restrict__ Wt) {
  __shared__ unsigned short tile[64 * 72];
  const int k0 = blockIdx.x * 64;   // 16
  const int n0 = blockIdx.y * 64;   // 48
  const int tid = threadIdx.x;
#pragma unroll
  for (int it = 0; it < 4; it++) {
    int idx = tid + it * 256;       // 1024 units of 4 el
    int r = idx >> 4, c4 = (idx & 15) * 4;   // r = k row, c4 = n col
    float4 f = *(const float4*)(W + (size_t)(k0 + r) * 3072 + n0 + c4);
    unsigned w0 = (unsigned)f2h(f.x) | ((unsigned)f2h(f.y) << 16);
    unsigned w1 = (unsigned)f2h(f.z) | ((unsigned)f2h(f.w) << 16);
    *(unsigned*)&tile[r * 72 + c4] = w0;
    *(unsigned*)&tile[r * 72 + c4 + 2] = w1;
  }
  __syncthreads();
#pragma unroll
  for (int it = 0; it < 4; it++) {
    int u = tid + it * 256;         // 1024 units of 4 el (k-dir)
    int n = u >> 4, k4 = (u & 15) * 4;
    unsigned short e0 = tile[(k4 + 0) * 72 + n];
    unsigned short e1 = tile[(k4 + 1) * 72 + n];
    unsigned short e2 = tile[(k4 + 2) * 72 + n];
    unsigned short e3 = tile[(k4 + 3) * 72 + n];
    uint2 pk;
    pk.x = (unsigned)e0 | ((unsigned)e1 << 16);
    pk.y = (unsigned)e2 | ((unsigned)e3 << 16);
    *(uint2*)(Wt + (size_t)(n0 + n) * 1024 + k0 + k4) = pk;
  }
}

// ---------------------------------------------------------------------------
// P3: dist_emb fp32 -> bf16.
// ---------------------------------------------------------------------------
__global__ __launch_bounds__(256) void emb_prep(const float* __restrict__ e,
                                                unsigned short* __restrict__ o) {
  int i = blockIdx.x * 256 + threadIdx.x;
  if (i < 2047 * 64) o[i] = f2bf(e[i]);
}

// ---------------------------------------------------------------------------
// K1: QKV projection, fp16 MFMA (m97 structure).  Unchanged (R4-proven).
// ---------------------------------------------------------------------------
__global__ __launch_bounds__(256, 2) void qkv_mfma(
    const unsigned short* __restrict__ Xh, const unsigned short* __restrict__ Wt,
    const float* __restrict__ bias, unsigned short* __restrict__ qkvg) {
  __shared__ __align__(16) char smem[32768];
  unsigned short* Asm = (unsigned short*)smem;            // [128][32] (no pad: glds)
  unsigned short* Bsm = (unsigned short*)(smem + 8192);   // [128][32]
  unsigned short* Cs  = (unsigned short*)smem;            // epilogue [128][128]

  const int tid = threadIdx.x;
  const int w = tid >> 6, lane = tid & 63;
  const int col = lane & 15, quad = lane >> 4;
  const int wm = (w >> 1) * 64, wn = (w & 1) * 64;
  const int bn = blockIdx.x * 128, bm = blockIdx.y * 128;

  const unsigned short* Ag = Xh + (size_t)bm * 1024;
  const unsigned short* Bg = Wt + (size_t)bn * 1024;
  const int ldrow = w * 32 + (lane >> 2);   // + it*16
  const int ldoff = (lane & 3) * 8;         // element offset in k

  f32x4 acc[4][4];
#pragma unroll
  for (int i = 0; i < 4; i++)
#pragma unroll
    for (int j = 0; j < 4; j++) acc[i][j] = (f32x4){0.f, 0.f, 0.f, 0.f};

  for (int k0 = 0; k0 < 1024; k0 += 32) {
    __syncthreads();
#pragma unroll
    for (int it = 0; it < 2; it++) {
      const unsigned short* ga = Ag + (size_t)(ldrow + it * 16) * 1024 + k0 + ldoff;
      const unsigned short* gb = Bg + (size_t)(ldrow + it * 16) * 1024 + k0 + ldoff;
      __builtin_amdgcn_global_load_lds(
          (const __attribute__((address_space(1))) unsigned*)ga,
          (__attribute__((address_space(3))) unsigned*)(Asm + (w * 32 + it * 16) * 32),
          16, 0, 0);
      __builtin_amdgcn_global_load_lds(
          (const __attribute__((address_space(1))) unsigned*)gb,
          (__attribute__((address_space(3))) unsigned*)(Bsm + (w * 32 + it * 16) * 32),
          16, 0, 0);
    }
    __syncthreads();
    f16x8 af[4], bf[4];
#pragma unroll
    for (int i = 0; i < 4; i++)
      af[i] = *(const f16x8*)&Asm[(wm + i * 16 + col) * 32 + quad * 8];
#pragma unroll
    for (int j = 0; j < 4; j++)
      bf[j] = *(const f16x8*)&Bsm[(wn + j * 16 + col) * 32 + quad * 8];
#pragma unroll
    for (int i = 0; i < 4; i++)
#pragma unroll
      for (int j = 0; j < 4; j++)
        acc[i][j] = MFMA16F(af[i], bf[j], acc[i][j]);
  }

  float bj[4];
#pragma unroll
  for (int j = 0; j < 4; j++) bj[j] = bias[bn + wn + j * 16 + col];

  __syncthreads();   // staging LDS dead; reuse as Cs
#pragma unroll
  for (int i = 0; i < 4; i++)
#pragma unroll
    for (int j = 0; j < 4; j++)
#pragma unroll
      for (int k = 0; k < 4; k++)
        Cs[(wm + i * 16 + quad * 4 + k) * 128 + wn + j * 16 + col] =
            f2bf(acc[i][j][k] + bj[j]);
  __syncthreads();

  const int t = bn >> 10;                       // uniform per block
  unsigned short* dst_base = qkvg + (size_t)t * HEAD_ELEMS;
#pragma unroll
  for (int it = 0; it < 8; it++) {
    int u = tid + it * 256;                     // 2048 units of 8 el
    int row = u >> 4, c8 = (u & 15) * 8;
    int m = bm + row;
    int n = bn + c8;
    int b = m >> 10, l = m & 1023;
    int cc = n & 1023, h = cc >> 6, d0 = cc & 63;
    uint4 val = *(const uint4*)&Cs[row * 128 + c8];
    *(uint4*)(dst_base + (((size_t)(b * 16 + h) * 1024 + l) * 64 + d0)) = val;
  }
}

// ---------------------------------------------------------------------------
// P4: V bf16 [bh][l][64] -> VT bf16 [bh][d][1024].
// ---------------------------------------------------------------------------
__global__ __launch_bounds__(256) void vt_prep_bf(const unsigned short* __restrict__ vg,
                                                  unsigned short* __restrict__ vtg) {
  __shared__ unsigned short tile[64 * 72];
  const int bh = blockIdx.x;
  const int rt = blockIdx.y * 64;
  const int tid = threadIdx.x;
  const unsigned short* src = vg + ((size_t)bh * Lq + rt) * HDq;
#pragma unroll
  for (int it = 0; it < 2; it++) {
    int idx = tid + it * 256;       // 512 units of 8 el
    int r = idx >> 3, o = (idx & 7) * 8;
    *(uint4*)&tile[r * 72 + o] = *(const uint4*)(src + (size_t)r * 64 + o);
  }
  __syncthreads();
  unsigned short* dst = vtg + (size_t)bh * HDq * Lq;
#pragma unroll
  for (int it = 0; it < 4; it++) {
    int u = tid + it * 256;         // 1024 units of 4 r
    int d = u >> 4, r4 = (u & 15) * 4;
    unsigned short e0 = tile[(r4 + 0) * 72 + d];
    unsigned short e1 = tile[(r4 + 1) * 72 + d];
    unsigned short e2 = tile[(r4 + 2) * 72 + d];
    unsigned short e3 = tile[(r4 + 3) * 72 + d];
    uint2 pk;
    pk.x = (unsigned)e0 | ((unsigned)e1 << 16);
    pk.y = (unsigned)e2 | ((unsigned)e3 << 16);
    *(uint2*)(dst + (size_t)d * Lq + rt + r4) = pk;
  }
}

// ---------------------------------------------------------------------------
// K2: MFMA flash attention (R6 dataflow, R6-proven 3-barrier structure).
// R8 delta: Ps aliases Qs (Q consumed to registers in prologue; Ps first
// written two barriers later — race-free).  LDS 63488 -> 54272 B, which is
// <= floor(160KiB/3) = 54613: allows 3 blocks/CU if LDS is the residency
// limiter.  launch_bounds stays (256,2) — R7 showed tighter bounds spill
// (~32 regs -> 170MB scratch traffic, 2x slowdown).
// ---------------------------------------------------------------------------
__global__ __launch_bounds__(256, 2) void attn_mfma(
    const unsigned short* __restrict__ qg, const unsigned short* __restrict__ kg,
    const unsigned short* __restrict__ vtg, const unsigned short* __restrict__ emb,
    float* __restrict__ out) {
  __shared__ __align__(16) char smem[54272];
  unsigned short* Qs  = (unsigned short*)smem;             // [64][72] (prologue only)
  unsigned short* Ps  = (unsigned short*)smem;             // alias: loop-time P
  unsigned short* Ks  = (unsigned short*)(smem + 9216);    // [64][72]
  unsigned short* VTs = (unsigned short*)(smem + 18432);   // [64 d][72]
  unsigned short* Pb  = (unsigned short*)(smem + 27648);   // [64][72] new band half
  unsigned short* B12 = (unsigned short*)(smem + 36864);   // [64][136] interleaved

  const int bh = blockIdx.x;
  const int l0 = blockIdx.y * 64;
  const int tid = threadIdx.x;
  const int w = tid >> 6, lane = tid & 63;
  const int col = lane & 15, quad = lane >> 4;
  const int lw = w * 16;

  const unsigned short* Qg = qg + ((size_t)bh * Lq + l0) * HDq;
  const unsigned short* Kg = kg + (size_t)bh * Lq * HDq;
  const unsigned short* VTgh = vtg + (size_t)bh * HDq * Lq;

  // ---- prologue: stage Q + upper band half (delta rows 64..127 of chunk 0) ----
#pragma unroll
  for (int it = 0; it < 2; it++) {
    int idx = tid + it * 256;       // 512 units of 8 el
    int r = idx >> 3, o = (idx & 7) * 8;
    *(uint4*)&Qs[r * 72 + o] = *(const uint4*)(Qg + (size_t)r * 64 + o);
    // upper half of chunk-0 band: emb rows (l0 + 960) + 64 + r
    int g = min(l0 + 1024 + r, 2046);
    *(uint4*)&Pb[r * 72 + o] = *(const uint4*)(emb + (size_t)g * 64 + o);
  }
  __syncthreads();

  bf16x8 qf[2];
#pragma unroll
  for (int ks = 0; ks < 2; ks++)
    qf[ks] = *(const bf16x8*)&Qs[(lw + col) * 72 + quad * 8 + ks * 32];

  // carried fragments: band rows 64+dt*16+col (dt'=4..7) of the current chunk
  bf16x8 sav[4][2];
#pragma unroll
  for (int dm = 0; dm < 4; dm++)
#pragma unroll
    for (int ks = 0; ks < 2; ks++)
      sav[dm][ks] = *(const bf16x8*)&Pb[(dm * 16 + col) * 72 + quad * 8 + ks * 32];

  f32x4 oacc[4];
#pragma unroll
  for (int nt = 0; nt < 4; nt++) oacc[nt] = (f32x4){0.f, 0.f, 0.f, 0.f};
  float mrow[4] = {-1e30f, -1e30f, -1e30f, -1e30f};
  float lrow[4] = {0.f, 0.f, 0.f, 0.f};

  for (int ch = 0; ch < 16; ch++) {
    const int r0 = ch * 64;
    __syncthreads();   // prior chunk's LDS reads (incl. B12, Pb, Ps) complete

    // ---- stage K chunk ----
#pragma unroll
    for (int it = 0; it < 2; it++) {
      int idx = tid + it * 256;
      int r = idx >> 3, o = (idx & 7) * 8;
      *(uint4*)&Ks[r * 72 + o] = *(const uint4*)(Kg + (size_t)(r0 + r) * 64 + o);
    }
    // ---- stage VT chunk ----
#pragma unroll
    for (int it = 0; it < 2; it++) {
      int idx = tid + it * 256;
      int d = idx >> 3, o = (idx & 7) * 8;
      *(uint4*)&VTs[d * 72 + o] = *(const uint4*)(VTgh + (size_t)d * Lq + r0 + o);
    }
    // ---- stage NEW band half: delta rows 0..63 = emb rows pb0 + r ----
    const int pb0 = l0 - r0 + 960;
#pragma unroll
    for (int it = 0; it < 2; it++) {
      int idx = tid + it * 256;     // 512 units of 8 el
      int r = idx >> 3, o = (idx & 7) * 8;
      *(uint4*)&Pb[r * 72 + o] = *(const uint4*)(emb + (size_t)(pb0 + r) * 64 + o);
    }
    __syncthreads();   // staging visible

    // ---- S = Q K^T ----
    bf16x8 kf[4][2];
#pragma unroll
    for (int rt = 0; rt < 4; rt++)
#pragma unroll
      for (int ks = 0; ks < 2; ks++)
        kf[rt][ks] = *(const bf16x8*)&Ks[(rt * 16 + col) * 72 + quad * 8 + ks * 32];
    f32x4 sac[4];
#pragma unroll
    for (int rt = 0; rt < 4; rt++) {
      f32x4 z = (f32x4){0.f, 0.f, 0.f, 0.f};
      z = MFMA16B(qf[0], kf[rt][0], z);
      z = MFMA16B(qf[1], kf[rt][1], z);
      sac[rt] = z;
    }

    bf16x8 kaf[2];
#pragma unroll
    for (int ks = 0; ks < 2; ks++)
      kaf[ks] = *(const bf16x8*)&Ks[(lw + col) * 72 + quad * 8 + ks * 32];

    // ---- D1/D2 GEMMs + shear scatter into B12 ----
    bf16x8 fresh[4][2];
#pragma unroll
    for (int dm = 0; dm < 4; dm++)
#pragma unroll
      for (int ks = 0; ks < 2; ks++)
        fresh[dm][ks] = *(const bf16x8*)&Pb[(dm * 16 + col) * 72 + quad * 8 + ks * 32];

#pragma unroll
    for (int dt = 0; dt < 8; dt++) {
      bf16x8 pbf0 = (dt < 4) ? fresh[dt & 3][0] : sav[dt & 3][0];
      bf16x8 pbf1 = (dt < 4) ? fresh[dt & 3][1] : sav[dt & 3][1];
      f32x4 z = (f32x4){0.f, 0.f, 0.f, 0.f};
      f32x4 y = (f32x4){0.f, 0.f, 0.f, 0.f};
      z = MFMA16B(qf[0], pbf0, z);
      z = MFMA16B(qf[1], pbf1, z);     // D1[l][delta]
      y = MFMA16B(kaf[0], pbf0, y);
      y = MFMA16B(kaf[1], pbf1, y);    // D2[r][delta]
      const int dcol = dt * 16 + col;  // delta band index j = l - r + 63
#pragma unroll
      for (int k = 0; k < 4; k++) {
        int l1 = lw + quad * 4 + k;
        int r1 = l1 - dcol + 63;
        if (r1 >= 0 && r1 < 64) B12[l1 * 136 + 2 * r1] = f2bf(z[k]);
        int r2 = lw + quad * 4 + k;
        int l2 = dcol - 63 + r2;
        if (l2 >= 0 && l2 < 64) B12[l2 * 136 + 2 * r2 + 1] = f2bf(y[k]);
      }
    }
    // carry: this chunk's fresh lower half == next chunk's upper half
#pragma unroll
    for (int dm = 0; dm < 4; dm++)
#pragma unroll
      for (int ks = 0; ks < 2; ks++)
        sav[dm][ks] = fresh[dm][ks];
    __syncthreads();   // bias writes visible (B12 is cross-wave)

    // ---- online softmax (C-layout: row = quad*4+k, col = lane&15) ----
    float p[4][4];
    float alpha[4];
#pragma unroll
    for (int k = 0; k < 4; k++) {
      int l1 = lw + quad * 4 + k;
      float st[4];
#pragma unroll
      for (int rt = 0; rt < 4; rt++) {
        int r = rt * 16 + col;
        unsigned pr = *(const unsigned*)&B12[l1 * 136 + 2 * r];
        float bias = bf2f((unsigned short)(pr & 0xFFFFu)) +
                     bf2f((unsigned short)(pr >> 16));
        st[rt] = (sac[rt][k] + bias) * 0.125f;
      }
      float mx = fmaxf(fmaxf(st[0], st[1]), fmaxf(st[2], st[3]));
      mx = fmaxf(mx, __shfl_xor(mx, 1));
      mx = fmaxf(mx, __shfl_xor(mx, 2));
      mx = fmaxf(mx, __shfl_xor(mx, 4));
      mx = fmaxf(mx, __shfl_xor(mx, 8));
      float mnew = fmaxf(mrow[k], mx);
      float a = __expf(mrow[k] - mnew);
      mrow[k] = mnew;
      alpha[k] = a;
      float ls = 0.f;
#pragma unroll
      for (int rt = 0; rt < 4; rt++) {
        p[rt][k] = __expf(st[rt] - mnew);
        ls += p[rt][k];
      }
      lrow[k] = lrow[k] * a + ls;
    }
#pragma unroll
    for (int nt = 0; nt < 4; nt++)
#pragma unroll
      for (int k = 0; k < 4; k++) oacc[nt][k] *= alpha[k];

    // ---- P -> LDS (A-layout), same-wave rows only (Ps aliases dead Qs) ----
#pragma unroll
    for (int rt = 0; rt < 4; rt++)
#pragma unroll
      for (int k = 0; k < 4; k++)
        Ps[(lw + quad * 4 + k) * 72 + rt * 16 + col] = f2bf(p[rt][k]);

    // ---- PV ----
    bf16x8 pf[2];
#pragma unroll
    for (int ks = 0; ks < 2; ks++)
      pf[ks] = *(const bf16x8*)&Ps[(lw + col) * 72 + quad * 8 + ks * 32];
#pragma unroll
    for (int nt = 0; nt < 4; nt++) {
      bf16x8 v0 = *(const bf16x8*)&VTs[(nt * 16 + col) * 72 + quad * 8];
      bf16x8 v1 = *(const bf16x8*)&VTs[(nt * 16 + col) * 72 + quad * 8 + 32];
      oacc[nt] = MFMA16B(pf[0], v0, oacc[nt]);
      oacc[nt] = MFMA16B(pf[1], v1, oacc[nt]);
    }
  }

  // ---- epilogue ----
  float inv[4];
#pragma unroll
  for (int k = 0; k < 4; k++) {
    float t = lrow[k];
    t += __shfl_xor(t, 1);
    t += __shfl_xor(t, 2);
    t += __shfl_xor(t, 4);
    t += __shfl_xor(t, 8);
    inv[k] = 1.0f / t;
  }
  const int b = bh >> 4, h = bh & 15;
#pragma unroll
  for (int nt = 0; nt < 4; nt++) {
#pragma unroll
    for (int k = 0; k < 4; k++) {
      int lg = l0 + lw + quad * 4 + k;
      int d = nt * 16 + col;
      out[(((size_t)b * Lq + lg) * Hq + h) * HDq + d] = oacc[nt][k] * inv[k];
    }
  }
}

// ---------------------------------------------------------------------------
extern "C" void kernel_launch(void* const* d_in, const int* in_sizes, int n_in,
                              void* d_out, int out_size, void* d_ws, size_t ws_size,
                              hipStream_t stream) {
  const float* x        = (const float*)d_in[0];
  const float* Wqkv     = (const float*)d_in[1];
  const float* bqkv     = (const float*)d_in[2];
  const float* dist_emb = (const float*)d_in[3];
  float* out = (float*)d_out;

  unsigned short* Xh   = (unsigned short*)d_ws;                              // 8 MB
  unsigned short* Wt   = (unsigned short*)((char*)d_ws + (8u << 20));        // 6 MB
  unsigned short* qkvg = (unsigned short*)((char*)d_ws + (16u << 20));       // 24 MB
  unsigned short* vtg  = (unsigned short*)((char*)d_ws + (40u << 20));       // 8 MB
  unsigned short* emb  = (unsigned short*)((char*)d_ws + (48u << 20));       // 256 KB

  x_prep<<<dim3(4096), dim3(256), 0, stream>>>(x, Xh);
  wt_prep<<<dim3(16, 48), dim3(256), 0, stream>>>(Wqkv, Wt);
  emb_prep<<<dim3(512), dim3(256), 0, stream>>>(dist_emb, emb);

  qkv_mfma<<<dim3(24, 32), dim3(256), 0, stream>>>(Xh, Wt, bqkv, qkvg);

  vt_prep_bf<<<dim3(BHq, Lq / 64), dim3(256), 0, stream>>>(qkvg + 2 * HEAD_ELEMS, vtg);

  attn_mfma<<<dim3(BHq, Lq / 64), dim3(256), 0, stream>>>(
      qkvg, qkvg + HEAD_ELEMS, vtg, emb, out);
}